// Round 8
// baseline (1099.117 us; speedup 1.0000x reference)
//
#include <hip/hip_runtime.h>

#define MAX_ITER 8192
#define NCHUNK   64
#define NCHUNKS  128          // MAX_ITER / NCHUNK
#define NSCAN    64           // scanner blocks, 1 sample each
#define NTHREADS 256

typedef unsigned long long u64;
#define KEY_MAX  0xffffffffffffffffull
#define POISON64 0xAAAAAAAAAAAAAAAAull   // d_ws re-poison pattern (0xAA bytes)

// IEEE fp32 ops, contraction off -> bitwise numpy match (verified many rounds).
__device__ __forceinline__ float mul_rn(float a, float b) {
#pragma clang fp contract(off)
  return a * b;
}
__device__ __forceinline__ float add_rn(float a, float b) {
#pragma clang fp contract(off)
  return a + b;
}
__device__ __forceinline__ float sub_rn(float a, float b) {
#pragma clang fp contract(off)
  return a - b;
}
__device__ __forceinline__ float dist2_rn(float px, float py, float sx, float sy) {
  const float dx = sub_rn(px, sx), dy = sub_rn(py, sy);
  return add_rn(mul_rn(dx, dx), mul_rn(dy, dy));
}
__device__ __forceinline__ float bcastf(float v, int lane) {
  return __int_as_float(__builtin_amdgcn_readlane(__float_as_int(v), lane));
}
__device__ __forceinline__ void st_agent(u64* p, u64 v) {
  __hip_atomic_store(p, v, __ATOMIC_RELAXED, __HIP_MEMORY_SCOPE_AGENT);
}
__device__ __forceinline__ u64 ld_agent(u64* p) {
  return __hip_atomic_load(p, __ATOMIC_RELAXED, __HIP_MEMORY_SCOPE_AGENT);
}
__device__ __forceinline__ u64 packf2(float x, float y) {
  return ((u64)__float_as_uint(y) << 32) | (u64)__float_as_uint(x);
}
__device__ __forceinline__ float lo32f(u64 v) {
  return __uint_as_float((unsigned)(v & 0xffffffffu));
}
__device__ __forceinline__ float hi32f(u64 v) {
  return __uint_as_float((unsigned)(v >> 32));
}
__device__ __forceinline__ void compiler_fence() {
  asm volatile("" ::: "memory");
}
// Exact (d2, idx) lex key: d2>=0 -> bit-monotone; ties -> lowest idx.
// idx bits 0..12 (max 8064); tag bits 13..20 (values 132..255; the 0xAA
// poison pattern decodes to tag 85 -> can never false-match).
__device__ __forceinline__ u64 mkkey(float d2, int idx) {
  return ((u64)__float_as_uint(d2) << 32) | (u64)(unsigned)idx;
}
__device__ __forceinline__ unsigned tagof(u64 kv) {
  return ((unsigned)(kv >> 13)) & 0xFFu;
}
__device__ __forceinline__ void load_sample(const float* __restrict__ u,
                                            const float* __restrict__ r,
                                            float gx, float gy, int idx,
                                            float& ox, float& oy) {
  const float uu = u[idx];
  if (uu < 0.1f) { ox = gx; oy = gy; }
  else { ox = mul_rn(r[2 * idx], 200.0f); oy = mul_rn(r[2 * idx + 1], 200.0f); }
}

__global__ __launch_bounds__(NTHREADS) void rrt_kernel(
    const float* __restrict__ state, const float* __restrict__ goal,
    const float* __restrict__ u, const float* __restrict__ r,
    float* __restrict__ out, unsigned* __restrict__ ws) {
  // scanners: staged node copy (bulk prescan source).
  // coordinator: its OWN self-copy (M-index -> coords via ds_read).
  __shared__ __align__(16) float2 nodesL[8064];
  __shared__ u64 sharedK[4];

  u64* outU  = (u64*)out;               // node i at outU[i] (float2-packed)
  // MbufK: 4-slot ring of 64 tagged keys.  Scanner iter i writes slot i&3,
  // tag i+132: M over [0..64(i+1)] computed vs chunk (i+4)'s samples.
  // Coordinator merge j (>=4) reads slot (j-4)&3 requiring tag == j+128
  // EXACTLY (tags are sample-specific -- r3 lesson).  Slot reuse (scanner
  // iter i+4, same slot) is gated on Nb chunk i+4, which the coordinator
  // publishes one full chunk AFTER merge j=i+4 consumed iter i's M.
  u64* MbufK = (u64*)(ws + 64);         // bytes 256..2303
  u64* Nb    = (u64*)(ws + 576);        // bytes 2304..67839
  // Nb[m] = node m+1, written ONCE; 0xAA poison is an impossible node value
  // (all nodes >= 0; 0xAAAAAAAA is negative).  Data IS the ready flag ->
  // no nflag, no vmcnt drain, no init guard.  u64 stores don't tear.

  const int tid  = threadIdx.x;
  const int wave = tid >> 6;
  const int lane = tid & 63;
  const int blk  = blockIdx.x;

  const float n0x = state[0], n0y = state[1];
  const float gx = goal[0],  gy = goal[1];

  if (blk == 0) {
    // ================= coordinator: one wave, no barriers ==================
    if (tid == 0) st_agent(&outU[0], packf2(n0x, n0y));   // node 0
    if (tid >= 64) return;

    // samples: s = chunk j, s1/s2/s3 = chunks j+1/j+2/j+3
    float sx, sy, s1x, s1y, s2x, s2y;
    load_sample(u, r, gx, gy, lane, sx, sy);
    load_sample(u, r, gx, gy, NCHUNK + lane, s1x, s1y);
    load_sample(u, r, gx, gy, 2 * NCHUNK + lane, s2x, s2y);
    // 3-deep value-form carries.  At merge j, c1 covers chunks j-3..j-1 vs
    // s_j (chunk j-3's nodes folded while it was c3, j-2's while c2, j-1's
    // while c1 -> ascending index order, strict < -> lowest idx on ties).
    float c1d = 3.0e38f, c1x = 0.0f, c1y = 0.0f;
    float c2d = 3.0e38f, c2x = 0.0f, c2y = 0.0f;
    float c3d = 3.0e38f, c3x = 0.0f, c3y = 0.0f;
    u64 kvPre = 0;

    for (int j = 0; j < NCHUNKS; ++j) {
      const int c = j * NCHUNK;

      // prefetch chunk j+3 sample (becomes s2 next iter via rotation)
      float s3x = 0.0f, s3y = 0.0f;
      if (j + 3 < NCHUNKS)
        load_sample(u, r, gx, gy, (j + 3) * NCHUNK + lane, s3x, s3y);

      // ---- merge argmin over [0..64j]:
      //   M (j>=4): [0..64(j-3)] incl node0; M wins ties (lower indices)
      //   c1: chunks j-3..j-1 (disjoint higher range, strict <)
      float bd2, bx, by;
      if (j >= 4) {
        const unsigned want = (unsigned)(j + 128);
        u64 kv = kvPre;   // issued late in chunk j-1 -> ~3 chunks after pub
        if (!__all((int)(tagof(kv) == want))) {
          u64* slot = MbufK + (((unsigned)(j - 4)) & 3u) * 64;
          for (;;) {
            kv = ld_agent(&slot[lane]);
            if (__all((int)(tagof(kv) == want))) break;
            __builtin_amdgcn_s_sleep(1);
          }
        }
        compiler_fence();
        bd2 = hi32f(kv);
        const unsigned midx = (unsigned)kv & 0x1FFFu;
        if (midx == 0u) { bx = n0x; by = n0y; }
        else { const float2 p = nodesL[midx - 1]; bx = p.x; by = p.y; }
      } else {
        bd2 = dist2_rn(n0x, n0y, sx, sy);
        bx = n0x; by = n0y;
      }
      if (c1d < bd2) { bd2 = c1d; bx = c1x; by = c1y; }

      // carry shift (AFTER merge)
      c1d = c2d; c1x = c2x; c1y = c2y;
      c2d = c3d; c2x = c3x; c2y = c3y;
      c3d = 3.0e38f; c3x = 0.0f; c3y = 0.0f;

      // pre-steer (verified math)
      float dirx = sub_rn(sx, bx), diry = sub_rn(sy, by);
      float dist = __fsqrt_rn(add_rn(bd2, 1e-12f));
      float scl = (dist > 5.0f) ? __fdiv_rn(5.0f, dist) : 1.0f;
      float nx = add_rn(bx, mul_rn(dirx, scl));
      float ny = add_rn(by, mul_rn(diry, scl));

      // ---- 64 sequential steps (r7's exact loop) + 3 carried folds
      #pragma unroll 8
      for (int t = 0; t < NCHUNK; ++t) {
        const float px = bcastf(nx, t);   // node c+t+1
        const float py = bcastf(ny, t);
        if (lane > t) {
          const float nd2 = dist2_rn(px, py, sx, sy);
          if (nd2 < bd2) {               // rare: recompute steer
            bd2 = nd2; bx = px; by = py;
            dirx = sub_rn(sx, bx); diry = sub_rn(sy, by);
            dist = __fsqrt_rn(add_rn(nd2, 1e-12f));
            scl = (dist > 5.0f) ? __fdiv_rn(5.0f, dist) : 1.0f;
            nx = add_rn(bx, mul_rn(dirx, scl));
            ny = add_rn(by, mul_rn(diry, scl));
          }
        }
        {  // carried folds (independent; issue in readlane-stall shadows)
          const float d1 = dist2_rn(px, py, s1x, s1y);
          if (d1 < c1d) { c1d = d1; c1x = px; c1y = py; }
          const float d2 = dist2_rn(px, py, s2x, s2y);
          if (d2 < c2d) { c2d = d2; c2x = px; c2y = py; }
          const float d3 = dist2_rn(px, py, s3x, s3y);
          if (d3 < c3d) { c3d = d3; c3x = px; c3y = py; }
        }
      }

      // speculative ring load for merge j+1 (slot (j-3)&3): issued here,
      // ~1 us of flight over publish+prefetch; target was published ~2-3
      // chunk-periods ago -> expect hit.  Stale -> fallback poll.
      if (j >= 3 && j < NCHUNKS - 1) {
        u64* ns = MbufK + (((unsigned)(j - 3)) & 3u) * 64;
        kvPre = ld_agent(&ns[lane]);
      }

      // publish: LDS self-copy + output + poison-gated broadcast.  No drain.
      if (c + lane < 8064) {
        float2 p; p.x = nx; p.y = ny;
        nodesL[c + lane] = p;             // node c+lane+1 at LDS idx c+lane
      }
      const u64 pv = packf2(nx, ny);
      st_agent(&outU[c + lane + 1], pv);
      st_agent(&Nb[c + lane], pv);

      sx = s1x; sy = s1y; s1x = s2x; s1y = s2y; s2x = s3x; s2y = s3y;
    }
  } else {
    // ================= scanners: blocks 1..64, one sample each =============
    // iter i (0..123): issue Nb load for chunk i; bulk-scan [1..64i] from LDS
    // (staged by prior iters) + node 0 under it; wave-0 tail validates the
    // fresh chunk-i nodes via the poison gate (arrival IS the signal -- no
    // nflag hop, no outU round-trip), folds one per lane, publishes tag
    // i+132 into ring slot i&3 (for merge j=i+4, vs chunk (i+4)'s samples).
    // ~3 chunk-periods of slack before consumption.
    const int b = blk - 1;

    for (int i = 0; i < NCHUNKS - 4; ++i) {
      const int c = i * NCHUNK;

      u64 nv = POISON64;
      if (wave == 0) nv = ld_agent(&Nb[c + lane]);   // issue early, check late

      // my sample: chunk i+4, slot b
      float sx, sy;
      load_sample(u, r, gx, gy, (i + 4) * NCHUNK + b, sx, sy);

      // ---- bulk scan of staged nodes [1..64i] + node 0 ----
      u64 key = KEY_MAX;
      if (tid == 0) key = mkkey(dist2_rn(n0x, n0y, sx, sy), 0);
      // 256 lanes stride node pairs; float4 = nodes (jj, jj+1), jj odd
      for (int jj = 1 + 2 * tid; jj < c; jj += 2 * NTHREADS) {
        const float4 p = *(const float4*)&nodesL[jj - 1];
        const u64 ka = mkkey(dist2_rn(p.x, p.y, sx, sy), jj);
        const u64 kb = mkkey(dist2_rn(p.z, p.w, sx, sy), jj + 1);
        if (ka < key) key = ka;     // lower idx first: exact argmin ties
        if (kb < key) key = kb;
      }
      #pragma unroll
      for (int m = 32; m >= 1; m >>= 1) {
        const u64 ok = __shfl_xor(key, m, 64);
        if (ok < key) key = ok;
      }
      if (lane == 0) sharedK[wave] = key;
      __syncthreads();                  // barrier A: partials ready

      // ---- wave-0 tail: validate fresh chunk i, fold, publish, stage ----
      if (wave == 0) {
        u64 kk = (lane < 4) ? sharedK[lane] : KEY_MAX;
        u64 ok = __shfl_xor(kk, 1, 64); if (ok < kk) kk = ok;
        ok = __shfl_xor(kk, 2, 64);     if (ok < kk) kk = ok;

        while (!__all((int)(nv != POISON64))) {   // data arrival = signal
          __builtin_amdgcn_s_sleep(1);
          nv = ld_agent(&Nb[c + lane]);
        }
        compiler_fence();
        const float px = lo32f(nv), py = hi32f(nv);
        {
          float2 p; p.x = px; p.y = py;
          nodesL[c + lane] = p;           // stage chunk i for future bulks
          const u64 ki = mkkey(dist2_rn(px, py, sx, sy), c + lane + 1);
          if (ki < kk) kk = ki;           // (d2,idx) key: order-free ties
        }
        #pragma unroll
        for (int m = 32; m >= 1; m >>= 1) {
          const u64 o2 = __shfl_xor(kk, m, 64);
          if (o2 < kk) kk = o2;
        }
        if (lane == 0) {
          u64* slot = MbufK + (((unsigned)i) & 3u) * 64;
          st_agent(&slot[b], kk | ((u64)(unsigned)(i + 132) << 13));
        }
      }
      // barrier B: gates next iter's bulk reads of freshly staged nodes and
      // sharedK reuse.
      __syncthreads();
    }
  }
}

extern "C" void kernel_launch(void* const* d_in, const int* in_sizes, int n_in,
                              void* d_out, int out_size, void* d_ws, size_t ws_size,
                              hipStream_t stream) {
  const float* state = (const float*)d_in[0];
  const float* goal  = (const float*)d_in[1];
  const float* u     = (const float*)d_in[2];
  const float* r     = (const float*)d_in[3];
  float* out = (float*)d_out;
  unsigned* ws = (unsigned*)d_ws;
  (void)in_sizes; (void)n_in; (void)out_size; (void)ws_size;
  rrt_kernel<<<NSCAN + 1, NTHREADS, 0, stream>>>(state, goal, u, r, out, ws);
}

// Round 9
// 716.836 us; speedup vs baseline: 1.5333x; 1.5333x over previous
//
#include <hip/hip_runtime.h>

#define MAX_ITER 8192
#define NCHUNK   64
#define NCHUNKS  128          // MAX_ITER / NCHUNK
#define NSCAN    64           // scanner blocks, 1 sample each
#define NTHREADS 256
#define MAGIC    0x13572468u

typedef unsigned long long u64;
#define KEY_MAX 0xffffffffffffffffull

// IEEE fp32 ops, contraction off -> bitwise numpy match (verified many rounds).
__device__ __forceinline__ float mul_rn(float a, float b) {
#pragma clang fp contract(off)
  return a * b;
}
__device__ __forceinline__ float add_rn(float a, float b) {
#pragma clang fp contract(off)
  return a + b;
}
__device__ __forceinline__ float sub_rn(float a, float b) {
#pragma clang fp contract(off)
  return a - b;
}
__device__ __forceinline__ float dist2_rn(float px, float py, float sx, float sy) {
  const float dx = sub_rn(px, sx), dy = sub_rn(py, sy);
  return add_rn(mul_rn(dx, dx), mul_rn(dy, dy));
}
__device__ __forceinline__ float bcastf(float v, int lane) {
  return __int_as_float(__builtin_amdgcn_readlane(__float_as_int(v), lane));
}
__device__ __forceinline__ void st_agent(u64* p, u64 v) {
  __hip_atomic_store(p, v, __ATOMIC_RELAXED, __HIP_MEMORY_SCOPE_AGENT);
}
__device__ __forceinline__ u64 ld_agent(u64* p) {
  return __hip_atomic_load(p, __ATOMIC_RELAXED, __HIP_MEMORY_SCOPE_AGENT);
}
__device__ __forceinline__ void st_agent32(unsigned* p, unsigned v) {
  __hip_atomic_store(p, v, __ATOMIC_RELAXED, __HIP_MEMORY_SCOPE_AGENT);
}
__device__ __forceinline__ unsigned ld_agent32(unsigned* p) {
  return __hip_atomic_load(p, __ATOMIC_RELAXED, __HIP_MEMORY_SCOPE_AGENT);
}
__device__ __forceinline__ u64 packf2(float x, float y) {
  return ((u64)__float_as_uint(y) << 32) | (u64)__float_as_uint(x);
}
__device__ __forceinline__ void waitcnt_vm0() {
  asm volatile("s_waitcnt vmcnt(0)" ::: "memory");
}
__device__ __forceinline__ void compiler_fence() {
  asm volatile("" ::: "memory");
}
// Exact (d2, idx) lexicographic key: d2 >= 0 -> bit-monotonic; ties -> low idx.
__device__ __forceinline__ u64 mkkey(float d2, int idx) {
  return ((u64)__float_as_uint(d2) << 32) | (u64)(unsigned)idx;
}

__global__ __launch_bounds__(NTHREADS) void rrt_kernel(
    const float* __restrict__ state, const float* __restrict__ goal,
    const float* __restrict__ u, const float* __restrict__ r,
    float* __restrict__ out, unsigned* __restrict__ ws) {
  // scanners: staged node copy (bulk prescan source).
  // coordinator: its OWN self-copy (M-index -> coords via ds_read, no MbufC).
  __shared__ __align__(16) float2 nodesL[8064];
  __shared__ u64 sharedK[4];

  u64* outU = (u64*)out;                // node i at outU[i] (float2-packed)
  unsigned* nflag = ws;                 // coordinator epoch       (byte 0)
  unsigned* ini   = ws + 32;            // init guard              (byte 128)
  u64* MbufK = (u64*)(ws + 64);         // 64 tagged keys          (byte 256)

  const int tid  = threadIdx.x;
  const int wave = tid >> 6;
  const int lane = tid & 63;
  const int blk  = blockIdx.x;

  const float n0x = state[0], n0y = state[1];
  const float gx = goal[0],  gy = goal[1];

  if (blk == 0) {
    // ================= coordinator: one wave, no barriers ==================
    if (tid == 0) {   // d_ws re-poisoned 0xAA each launch
      st_agent32(nflag, 0u);
      st_agent(&outU[0], packf2(n0x, n0y));   // node 0
      waitcnt_vm0();
      st_agent32(ini, MAGIC);
    }
    if (tid >= 64) return;

    // current-chunk sample (chunk 0)
    float sx, sy;
    {
      const float uu = u[lane];
      if (uu < 0.1f) { sx = gx; sy = gy; }
      else { sx = mul_rn(r[2 * lane], 200.0f); sy = mul_rn(r[2 * lane + 1], 200.0f); }
    }
    float cbd2 = 3.0e38f, cbx = 0.0f, cby = 0.0f;   // carry over (c-64, c]
    u64 kvPre = 0;                                   // speculative MbufK preload

    for (int k = 0; k < NCHUNKS; ++k) {
      const int c = k * NCHUNK;
      const bool hasNext = (k < NCHUNKS - 1);

      // prefetch next-chunk sample (independent loads; also gives the
      // in-flight kvPre time to land)
      float nsx = 0.0f, nsy = 0.0f;
      if (hasNext) {
        const int i2 = c + NCHUNK + lane;
        const float uu = u[i2];
        if (uu < 0.1f) { nsx = gx; nsy = gy; }
        else { nsx = mul_rn(r[2 * i2], 200.0f); nsy = mul_rn(r[2 * i2 + 1], 200.0f); }
      }

      // ---- assemble argmin over [0..c]: scanner M [0..c-64] + carry (c-64,c]
      float bd2, bx, by;
      if (k == 0) {
        bd2 = dist2_rn(n0x, n0y, sx, sy);
        bx = n0x; by = n0y;
      } else {
        u64 kv = kvPre;   // issued right after previous epoch's nflag store
        if (!__all((int)(((unsigned)(kv >> 13) & 0x7Fu) == (unsigned)k))) {
          for (;;) {   // fallback poll: one coalesced load, all 64 must match
            kv = ld_agent(&MbufK[lane]);
            if (__all((int)(((unsigned)(kv >> 13) & 0x7Fu) == (unsigned)k))) break;
            __builtin_amdgcn_s_sleep(1);
          }
        }
        compiler_fence();
        const float md2 = __uint_as_float((unsigned)(kv >> 32));
        const unsigned midx = (unsigned)kv & 0x1FFFu;
        bd2 = cbd2; bx = cbx; by = cby;
        if (!(bd2 < md2)) {   // M's indices are all lower: M wins ties
          bd2 = md2;
          if (midx == 0u) { bx = n0x; by = n0y; }
          else { const float2 p = nodesL[midx - 1]; bx = p.x; by = p.y; }
        }
      }

      // pre-steer (verified math)
      float dirx = sub_rn(sx, bx), diry = sub_rn(sy, by);
      float dist = __fsqrt_rn(add_rn(bd2, 1e-12f));
      float scl = (dist > 5.0f) ? __fdiv_rn(5.0f, dist) : 1.0f;
      float nx = add_rn(bx, mul_rn(dirx, scl));
      float ny = add_rn(by, mul_rn(diry, scl));

      // ---- scan + candidate pops: EXACT sequential semantics.
      // Sequential step t (lane>t): if dist2(q_t, s_lane) < bd2 -> update +
      // steer.  A lane's state freezes once step==lane passes (folds only
      // t<lane).  Scan bits (computed from pre-event q) cover every event
      // whose q_t is unchanged (bd2 only decreases -> the witnessing lane's
      // scan comparison was already true); events at steps whose q changed
      // are re-added via ballot(upd) at the pop that changed them.  Pops
      // ascend (added bits are > t), each step pops <= once -> <= 64 pops;
      // pop-time recompute of d and upd gives bit-exact sequential behavior.
      u64 cand;
      {
        unsigned candLo = 0u, candHi = 0u;
        #pragma unroll
        for (int t = 0; t < NCHUNK; ++t) {
          const float px = bcastf(nx, t);
          const float py = bcastf(ny, t);
          const float d = dist2_rn(px, py, sx, sy);
          const u64 bal = __ballot(d < bd2);
          const u64 hi = (t < 63) ? (bal >> (t + 1)) : 0ull;   // lanes > t
          if (t < 32) candLo |= (hi != 0ull) ? (1u << t) : 0u;
          else        candHi |= (hi != 0ull) ? (1u << (t - 32)) : 0u;
        }
        cand = ((u64)candHi << 32) | (u64)candLo;
      }
      while (cand) {
        const int t = (int)__builtin_ctzll(cand);
        cand &= (cand - 1);
        const float px = bcastf(nx, t);
        const float py = bcastf(ny, t);
        const float d = dist2_rn(px, py, sx, sy);
        const bool upd = (lane > t) && (d < bd2);
        const u64 ub = __ballot(upd);
        if (ub != 0ull) {
          if (upd) {            // exact r7 update body
            bd2 = d; bx = px; by = py;
            dirx = sub_rn(sx, bx); diry = sub_rn(sy, by);
            dist = __fsqrt_rn(add_rn(d, 1e-12f));
            scl = (dist > 5.0f) ? __fdiv_rn(5.0f, dist) : 1.0f;
            nx = add_rn(bx, mul_rn(dirx, scl));
            ny = add_rn(by, mul_rn(diry, scl));
          }
          cand |= ub;           // updated lanes' steps become candidates (>t)
        }
      }

      // publish: LDS self-copy (for M-index resolution) + global + flag
      if (c + lane < 8064) {
        float2 p; p.x = nx; p.y = ny;
        nodesL[c + lane] = p;             // node c+lane+1 at LDS idx c+lane
      }
      st_agent(&outU[c + lane + 1], packf2(nx, ny));
      waitcnt_vm0();                     // wave-level drain of all 64 stores
      if (lane == 0 && hasNext) st_agent32(nflag, (unsigned)(k + 1));
      compiler_fence();
      // speculative preload AFTER nflag (off the drain path); stale -> poll
      if (hasNext) kvPre = ld_agent(&MbufK[lane]);

      // ---- carry fold (chunk's final nodes vs next sample): moved OUT of
      // the serial path; runs in the scanner-response shadow after publish.
      // Ascending t, strict < -> identical result/ties to r7's in-loop fold.
      float nbd2 = 3.0e38f, nbx = 0.0f, nby = 0.0f;
      if (hasNext) {
        #pragma unroll
        for (int t = 0; t < NCHUNK; ++t) {
          const float px = bcastf(nx, t);
          const float py = bcastf(ny, t);
          const float d = dist2_rn(px, py, nsx, nsy);
          if (d < nbd2) { nbd2 = d; nbx = px; nby = py; }
        }
      }

      cbd2 = nbd2; cbx = nbx; cby = nby;
      sx = nsx; sy = nsy;
    }
  } else {
    // ================= scanners: blocks 1..64, one sample each =============
    // (byte-identical to round 7)
    const int b = blk - 1;
    if (tid == 0) {
      while (ld_agent32(ini) != MAGIC) __builtin_amdgcn_s_sleep(2);
      compiler_fence();
    }
    __syncthreads();

    for (int k = 0; k < NCHUNKS - 1; ++k) {
      const int c  = k * NCHUNK;
      const int cb = c - NCHUNK;        // bulk top: nodes [1..cb] in LDS

      // my sample: chunk k+1, slot b
      float sx, sy;
      {
        const int i = (k + 1) * NCHUNK + b;
        const float uu = u[i];
        if (uu < 0.1f) { sx = gx; sy = gy; }
        else { sx = mul_rn(r[2 * i], 200.0f); sy = mul_rn(r[2 * i + 1], 200.0f); }
      }

      // ---- bulk scan (no dependence on current epoch) ----
      u64 key = KEY_MAX;
      if (tid == 0) {   // node 0
        key = mkkey(dist2_rn(n0x, n0y, sx, sy), 0);
      }
      // 256 lanes stride node pairs; float4 = nodes (j, j+1), j odd
      for (int j = 1 + 2 * tid; j < cb; j += 2 * NTHREADS) {
        const float4 p = *(const float4*)&nodesL[j - 1];
        const u64 ka = mkkey(dist2_rn(p.x, p.y, sx, sy), j);
        const u64 kb = mkkey(dist2_rn(p.z, p.w, sx, sy), j + 1);
        if (ka < key) key = ka;     // lower idx first: exact argmin ties
        if (kb < key) key = kb;
      }
      #pragma unroll
      for (int m = 32; m >= 1; m >>= 1) {
        const u64 ok = __shfl_xor(key, m, 64);
        if (ok < key) key = ok;
      }
      if (lane == 0) sharedK[wave] = key;
      __syncthreads();                  // barrier A: partials ready

      // ---- epoch-gated tail: wave 0 only ----
      if (wave == 0) {
        u64 kk = (lane < 4) ? sharedK[lane] : KEY_MAX;
        u64 ok = __shfl_xor(kk, 1, 64); if (ok < kk) kk = ok;
        ok = __shfl_xor(kk, 2, 64);     if (ok < kk) kk = ok;

        if (k >= 1) {   // fresh nodes (cb, c], one per lane
          while (ld_agent32(nflag) < (unsigned)k) __builtin_amdgcn_s_sleep(1);
          compiler_fence();
          const int j = cb + 1 + lane;
          const u64 nv = ld_agent(&outU[j]);
          const float px = __uint_as_float((unsigned)(nv & 0xffffffffu));
          const float py = __uint_as_float((unsigned)(nv >> 32));
          float2 p; p.x = px; p.y = py;
          nodesL[j - 1] = p;            // stage for future bulk scans
          const u64 ki = mkkey(dist2_rn(px, py, sx, sy), j);
          if (ki < kk) kk = ki;         // (d2,idx) key: tie-break order-free
        }
        #pragma unroll
        for (int m = 32; m >= 1; m >>= 1) {
          const u64 o2 = __shfl_xor(kk, m, 64);
          if (o2 < kk) kk = o2;
        }
        if (lane == 0) {
          st_agent(&MbufK[b], kk | ((u64)(unsigned)(k + 1) << 13));
        }
      }
      // barrier B: gates next iter's bulk reads of freshly staged nodes and
      // sharedK reuse.
      __syncthreads();
    }
  }
}

extern "C" void kernel_launch(void* const* d_in, const int* in_sizes, int n_in,
                              void* d_out, int out_size, void* d_ws, size_t ws_size,
                              hipStream_t stream) {
  const float* state = (const float*)d_in[0];
  const float* goal  = (const float*)d_in[1];
  const float* u     = (const float*)d_in[2];
  const float* r     = (const float*)d_in[3];
  float* out = (float*)d_out;
  unsigned* ws = (unsigned*)d_ws;
  (void)in_sizes; (void)n_in; (void)out_size; (void)ws_size;
  rrt_kernel<<<NSCAN + 1, NTHREADS, 0, stream>>>(state, goal, u, r, out, ws);
}